// Round 15
// baseline (314.819 us; speedup 1.0000x reference)
//
#include <hip/hip_runtime.h>
#include <hip/hip_bf16.h>

#define BB 2
#define CC 128
#define HH 128
#define WW 256
#define HWs (HH*WW)          // 32768
#define PI_F 3.14159265358979323846f

typedef __attribute__((ext_vector_type(8))) short bf16x8;
typedef __attribute__((ext_vector_type(8))) unsigned short u16x8;
typedef __attribute__((ext_vector_type(4))) float f32x4;
typedef __attribute__((ext_vector_type(2))) float f32x2;

__device__ __forceinline__ ushort f2bf(float f) {   // RNE
  uint u = __float_as_uint(f);
  u = (u + 0x7fffu + ((u >> 16) & 1u)) >> 16;
  return (ushort)u;
}
__device__ __forceinline__ float bf2f(ushort u) {
  return __uint_as_float(((uint)u) << 16);
}
// combine 4 bf16-pairs (uint each) with weights -> packed bf16 pair (pk-fma)
__device__ __forceinline__ uint comb4(uint u0, uint u1, uint u2, uint u3,
                                      f32x2 g0, f32x2 g1, f32x2 g2, f32x2 g3) {
  f32x2 a0 = (f32x2){__uint_as_float(u0 << 16), __uint_as_float(u0 & 0xffff0000u)};
  f32x2 a1 = (f32x2){__uint_as_float(u1 << 16), __uint_as_float(u1 & 0xffff0000u)};
  f32x2 a2 = (f32x2){__uint_as_float(u2 << 16), __uint_as_float(u2 & 0xffff0000u)};
  f32x2 a3 = (f32x2){__uint_as_float(u3 << 16), __uint_as_float(u3 & 0xffff0000u)};
  f32x2 s = a0 * g0 + a1 * g1 + a2 * g2 + a3 * g3;   // v_pk_fma_f32
  uint ua = __float_as_uint(s.x) + 0x8000u;
  uint ub = __float_as_uint(s.y) + 0x8000u;
  return (ua >> 16) | (ub & 0xffff0000u);
}

// ---- fused: weight/twiddle packing (blocks 0..283) + x->xt NHWC transpose
__global__ __launch_bounds__(256) void prep_kernel(
    const float* __restrict__ bw, const float* __restrict__ dw,
    const float* __restrict__ ow, const float* __restrict__ gw,
    const float* __restrict__ x,
    ushort* __restrict__ apkF, ushort* __restrict__ apkA,
    ushort* __restrict__ a1, ushort* __restrict__ a2,
    ushort* __restrict__ xt) {
  __shared__ ushort sT[64][128];
  int bid = blockIdx.x;
  int tid = threadIdx.x;
  if (bid >= 284) {
    int blk = bid - 284;              // 1024 = 2b * 128h * 4wt
    int wt = blk & 3, h = (blk >> 2) & 127, b = blk >> 9;
    int t = tid;
    const float* xb = x + ((size_t)b * CC * HH + h) * WW;
    ushort* ob = xt + (((size_t)b * HH + h) * WW) * 128;
    {
      int w = t & 63;
      int sw = (w & 7) << 3;
#pragma unroll
      for (int it = 0; it < 4; ++it) {
        int oct = (t >> 6) + it * 4;
        u16x8 v;
#pragma unroll
        for (int j = 0; j < 8; ++j)
          v[j] = f2bf(xb[(size_t)(oct * 8 + j) * HWs + wt * 64 + w]);
        *(u16x8*)&sT[w][(oct << 3) ^ sw] = v;
      }
    }
    __syncthreads();
#pragma unroll
    for (int it = 0; it < 4; ++it) {
      int u = t + it * 256;
      int w = u >> 4, oct = u & 15;
      u16x8 v = *(const u16x8*)&sT[w][(oct << 3) ^ ((w & 7) << 3)];
      *(u16x8*)&ob[(size_t)(wt * 64 + w) * 128 + oct * 8] = v;
    }
    return;
  }
  if (bid < 144) {
    int gid = bid * 256 + tid;
    int lane = gid & 63;
    int kf = (gid >> 6) & 3;
    int mf = (gid >> 8) & 7;
    int chunk = gid >> 11;
    int part = chunk >= 9;
    int tap = part ? chunk - 9 : chunk;
    int m = mf * 16 + (lane & 15);
    int cb = kf * 32 + ((lane >> 4) << 3);
    const float* src = part ? dw : bw;
    ushort* dst = apkF + (size_t)gid * 8;
#pragma unroll
    for (int j = 0; j < 8; ++j)
      dst[j] = f2bf(src[(size_t)m * 1152 + (size_t)(cb + j) * 9 + tap]);
  } else if (bid < 212) {
    int gid = (bid - 144) * 256 + tid;
    if (gid >= 17280) return;
    int lane = gid & 63;
    int kf = (gid >> 6) % 5;
    int mf = (gid / 320) % 6;
    int tap = gid / 1920;
    int m = mf * 16 + (lane & 15);
    int cb = kf * 32 + ((lane >> 4) << 3);
#pragma unroll
    for (int j = 0; j < 8; ++j) {
      int c = cb + j;
      float v = 0.f;
      if (c < 133) {
        if (m < 18) v = ow[(size_t)m * 1197 + c * 9 + tap];
        else if (m < 84) v = gw[(size_t)(m - 18) * 1197 + c * 9 + tap];
      }
      apkA[(size_t)gid * 8 + j] = f2bf(v);
    }
  } else {
    int gid = (bid - 212) * 256 + tid;
    if (gid < 10240) {
      int lane = gid & 63, kf = (gid >> 6) & 7, mf = gid >> 9;
      int m = mf * 16 + (lane & 15);
      int kk0 = kf * 32 + ((lane >> 4) << 3);
#pragma unroll
      for (int j = 0; j < 8; ++j) {
        int kk = kk0 + j;
        float v = 0.f;
        if (m < 129)      { int tt = (m * kk) & 255;         v =  cosf(tt * (PI_F / 128.f)); }
        else if (m < 258) { int tt = ((m - 129) * kk) & 255; v = -sinf(tt * (PI_F / 128.f)); }
        a1[(size_t)gid * 8 + j] = f2bf(v);
      }
    } else if (gid < 18432) {
      int q = gid - 10240;
      int lane = q & 63, kf = (q >> 6) & 7, mf = q >> 9;
      int m = mf * 16 + (lane & 15);
      int g = m & 127;
      int kk0 = kf * 32 + ((lane >> 4) << 3);
#pragma unroll
      for (int j = 0; j < 8; ++j) {
        int kk = kk0 + j;
        int h2 = kk & 127;
        int tt = (g * h2) & 127;
        float ang = tt * (PI_F / 64.f);
        float v = (m < 128) ? ((kk < 128) ? cosf(ang) : sinf(ang))
                            : ((kk < 128) ? -sinf(ang) : cosf(ang));
        a2[(size_t)q * 8 + j] = f2bf(v);
      }
    }
  }
}

// ---- DFT stage 1 (along W), MFMA. Grid 512: (bc, nh) split.
__global__ __launch_bounds__(256) void dft1_kernel(const float* __restrict__ x,
    const ushort* __restrict__ a1pk, ushort* __restrict__ F1) {
  int bid = blockIdx.x;
  int bc = bid >> 1, nh = bid & 1;
  int t = threadIdx.x, lane = t & 63, wv = t >> 6;
  int q8 = (lane >> 4) << 3, rq = (lane >> 4) << 2;
  const bf16x8* APK = (const bf16x8*)a1pk;
  ushort* f1b = F1 + (size_t)bc * 36864;
  f32x4 acc[5][4];
#pragma unroll
  for (int i = 0; i < 5; ++i)
#pragma unroll
    for (int n = 0; n < 4; ++n) acc[i][n] = (f32x4){0.f, 0.f, 0.f, 0.f};
  for (int kf = 0; kf < 8; ++kf) {
    bf16x8 av[5];
#pragma unroll
    for (int i = 0; i < 5; ++i)
      av[i] = APK[(size_t)((wv * 5 + i) * 8 + kf) * 64 + lane];
#pragma unroll
    for (int n2 = 0; n2 < 4; ++n2) {
      int nf = nh * 4 + n2;
      int hh = nf * 16 + (lane & 15);
      const float* xp = x + (((size_t)bc * HH + hh) << 8) + kf * 32 + q8;
      float4 xa = *(const float4*)xp;
      float4 xb4 = *(const float4*)(xp + 4);
      bf16x8 bv;
      bv[0] = (short)f2bf(xa.x); bv[1] = (short)f2bf(xa.y);
      bv[2] = (short)f2bf(xa.z); bv[3] = (short)f2bf(xa.w);
      bv[4] = (short)f2bf(xb4.x); bv[5] = (short)f2bf(xb4.y);
      bv[6] = (short)f2bf(xb4.z); bv[7] = (short)f2bf(xb4.w);
#pragma unroll
      for (int i = 0; i < 5; ++i)
        acc[i][n2] = __builtin_amdgcn_mfma_f32_16x16x32_bf16(av[i], bv, acc[i][n2], 0, 0, 0);
    }
  }
#pragma unroll
  for (int n2 = 0; n2 < 4; ++n2) {
    int hh = (nh * 4 + n2) * 16 + (lane & 15);
#pragma unroll
    for (int i = 0; i < 5; ++i) {
#pragma unroll
      for (int r = 0; r < 4; ++r) {
        int m = (wv * 5 + i) * 16 + rq + r;
        if (m < 258) {
          int sel = m >= 129;
          int k = sel ? m - 129 : m;
          f1b[(size_t)k * 256 + sel * 128 + hh] = f2bf(acc[i][n2][r]);
        }
      }
    }
  }
}

// ---- DFT stage 2 (along H) + magnitude. Grid 768: (bc, ng) split.
__global__ __launch_bounds__(256) void dft2_kernel(const ushort* __restrict__ F1,
    const ushort* __restrict__ a2pk, float* __restrict__ magbuf) {
  int bid = blockIdx.x;
  int bc = bid / 3, ng = bid % 3;
  int t = threadIdx.x, lane = t & 63, wv = t >> 6;
  int q8 = (lane >> 4) << 3, rq = (lane >> 4) << 2;
  const bf16x8* APK = (const bf16x8*)a2pk;
  const ushort* f1b = F1 + (size_t)bc * 36864;
  float* mb = magbuf + (size_t)bc * 18432;
  f32x4 acc[4][3];
#pragma unroll
  for (int i = 0; i < 4; ++i)
#pragma unroll
    for (int n = 0; n < 3; ++n) acc[i][n] = (f32x4){0.f, 0.f, 0.f, 0.f};
  for (int kf = 0; kf < 8; ++kf) {
    bf16x8 av[4];
#pragma unroll
    for (int i = 0; i < 4; ++i) {
      int mf = (i < 2) ? (2 * wv + i) : (2 * wv + (i - 2) + 8);
      av[i] = APK[(size_t)(mf * 8 + kf) * 64 + lane];
    }
#pragma unroll
    for (int n2 = 0; n2 < 3; ++n2) {
      int nf = ng * 3 + n2;
      int krow = nf * 16 + (lane & 15);
      bf16x8 bv = *(const bf16x8*)&f1b[(size_t)krow * 256 + kf * 32 + q8];
#pragma unroll
      for (int i = 0; i < 4; ++i)
        acc[i][n2] = __builtin_amdgcn_mfma_f32_16x16x32_bf16(av[i], bv, acc[i][n2], 0, 0, 0);
    }
  }
#pragma unroll
  for (int n2 = 0; n2 < 3; ++n2) {
    int k = (ng * 3 + n2) * 16 + (lane & 15);
    if (k < 129) {
#pragma unroll
      for (int pr = 0; pr < 2; ++pr) {
#pragma unroll
        for (int r = 0; r < 4; ++r) {
          int g = (2 * wv + pr) * 16 + rq + r;
          float vr = acc[pr][n2][r], vi = acc[pr + 2][n2][r];
          mb[(size_t)g * 144 + k] = sqrtf(vr * vr + vi * vi);
        }
      }
    }
  }
}

// ---- reduce magnitude over channels -> fe[b][g][129].
__global__ __launch_bounds__(256) void fe_reduce_kernel(const float* __restrict__ magbuf,
    float* __restrict__ fe) {
  int bid = blockIdx.x;
  int i = (bid >> 3) * 256 + threadIdx.x;   // 36864
  int cq = bid & 7;
  if (i >= 36864) return;
  int k = i % 144;
  int gb = i / 144;
  int g = gb & 127, b = gb >> 7;
  if (k >= 129) return;
  const float* mp = magbuf + (size_t)b * 128 * 18432 + (size_t)g * 144 + k
                  + (size_t)cq * 16 * 18432;
  float s = 0.f;
#pragma unroll
  for (int c = 0; c < 16; ++c) s += mp[(size_t)c * 18432];
  atomicAdd(&fe[((size_t)b * 128 + g) * 129 + k],
            s * (1.0f / (181.01933598375618f * 128.0f)));
}

// ---- aux conv v2 (R12): 3-row LDS window per channel-half, direct B reads
__global__ __launch_bounds__(256) void aux_conv_kernel(
    const ushort* __restrict__ xt, const float* __restrict__ fe,
    const ushort* __restrict__ apk,
    const float* __restrict__ offset_b, const float* __restrict__ gate_b1,
    const float* __restrict__ w2, const float* __restrict__ b2,
    float* __restrict__ offs, float* __restrict__ gate) {
  __shared__ ushort Win3[3 * 68 * 64];   // 26,112 B
  __shared__ ushort coordS[204 * 8];     // 3,264 B
  __shared__ float gldP[64][8];          // 2,048 B
  int t = threadIdx.x;
  int bid = blockIdx.x;
  int lin = (bid & 7) * 128 + (bid >> 3);
  int bz = lin >> 9;
  int rest = lin & 511;
  int h = rest >> 2, w0 = (rest & 3) << 6;
  int lane = t & 63, wid = t >> 6;
  int wm = wid >> 1, wn = wid & 1;
  int l15 = lane & 15, lg = lane >> 4;
  int rq = lg << 2;
  const bf16x8* APK = (const bf16x8*)apk;
  const ushort* xtb = xt + (size_t)bz * 4194304;
  const bf16x8 zvb = (bf16x8){0, 0, 0, 0, 0, 0, 0, 0};

  if (t < 204) {
    int r = t / 68, c = t - r * 68;
    int gy = h - 1 + r, gx = w0 - 2 + c;
    u16x8 v = (u16x8){0, 0, 0, 0, 0, 0, 0, 0};
    if ((unsigned)gy < 128u && (unsigned)gx < 256u) {
      float th = -PI_F + (float)gx * (2.0f * PI_F / 255.0f);
      float ph = -0.5f * PI_F + (float)gy * (PI_F / 127.0f);
      float sxc = ((float)gx + 0.5f) * (129.0f / 256.0f) - 0.5f;
      float fx = floorf(sxc);
      int x0 = (int)fx;
      float fr = sxc - fx;
      int x1 = min(x0 + 1, 128);
      x0 = max(x0, 0);
      const float* fb = fe + ((size_t)bz * 128 + gy) * 129;
      float fv = fb[x0] * (1.f - fr) + fb[x1] * fr;
      v[0] = f2bf(sinf(th)); v[1] = f2bf(cosf(th));
      v[2] = f2bf(sinf(ph)); v[3] = f2bf(cosf(ph));
      v[4] = f2bf(fv);
    }
    *(u16x8*)&coordS[t * 8] = v;
  }

  f32x4 acc[3][2];
#pragma unroll
  for (int i = 0; i < 3; ++i) {
    acc[i][0] = (f32x4){0.f, 0.f, 0.f, 0.f};
    acc[i][1] = (f32x4){0.f, 0.f, 0.f, 0.f};
  }
  int p0 = wn * 32 + l15, p1 = p0 + 16;

  for (int half = 0; half < 2; ++half) {
    if (half) __syncthreads();
    for (int it = 0; it < 7; ++it) {
      int u = it * 256 + t;
      if (u < 1632) {
        int s = u & 7;
        int c = (u >> 3) % 68;
        int r = u / 544;
        int gy = h - 1 + r, gx = w0 - 2 + c;
        u16x8 v = (u16x8){0, 0, 0, 0, 0, 0, 0, 0};
        if ((unsigned)gy < 128u && (unsigned)gx < 256u)
          v = *(const u16x8*)&xtb[((((size_t)gy << 8) + gx) << 7) + (half << 6) + (s << 3)];
        *(u16x8*)&Win3[((r * 68 + c) << 6) + ((s ^ (c & 7)) << 3)] = v;
      }
    }
    __syncthreads();

    for (int tap = 0; tap < 9; ++tap) {
      int ky = tap / 3 - 1, kx = tap % 3 - 1;
      int rr = ky + 1;
      int c0 = p0 + kx + 2, c1 = p1 + kx + 2;
      int nkf = half ? 3 : 2;
      for (int kfi = 0; kfi < nkf; ++kfi) {
        bf16x8 b0, b1;
        int kf;
        if (kfi < 2) {
          kf = half * 2 + kfi;
          int s = kfi * 4 + lg;
          b0 = *(const bf16x8*)&Win3[((rr * 68 + c0) << 6) + ((s ^ (c0 & 7)) << 3)];
          b1 = *(const bf16x8*)&Win3[((rr * 68 + c1) << 6) + ((s ^ (c1 & 7)) << 3)];
        } else {
          kf = 4;
          b0 = (lg == 0) ? *(const bf16x8*)&coordS[(rr * 68 + c0) * 8] : zvb;
          b1 = (lg == 0) ? *(const bf16x8*)&coordS[(rr * 68 + c1) * 8] : zvb;
        }
        int fb = (tap * 6 + wm * 3) * 5 + kf;
#pragma unroll
        for (int mfi = 0; mfi < 3; ++mfi) {
          bf16x8 av = APK[(size_t)(fb + mfi * 5) * 64 + lane];
          acc[mfi][0] = __builtin_amdgcn_mfma_f32_16x16x32_bf16(av, b0, acc[mfi][0], 0, 0, 0);
          acc[mfi][1] = __builtin_amdgcn_mfma_f32_16x16x32_bf16(av, b1, acc[mfi][1], 0, 0, 0);
        }
      }
    }
  }

  float gp[2] = {0.f, 0.f};
#pragma unroll
  for (int nf = 0; nf < 2; ++nf) {
    int p = wn * 32 + nf * 16 + l15;
    int w = w0 + p;
#pragma unroll
    for (int mfi = 0; mfi < 3; ++mfi) {
#pragma unroll
      for (int r = 0; r < 4; ++r) {
        int oc = wm * 48 + mfi * 16 + rq + r;
        float v = acc[mfi][nf][r];
        if (oc < 18) {
          offs[((size_t)bz * 18 + oc) * HWs + h * WW + w] = v + offset_b[oc];
        } else if (oc < 84) {
          gp[nf] += w2[oc - 18] * fmaxf(v + gate_b1[oc - 18], 0.f);
        }
      }
    }
  }
  gldP[p0][wm * 4 + lg] = gp[0];
  gldP[p1][wm * 4 + lg] = gp[1];
  __syncthreads();
  if (t < 64) {
    float s = b2[0];
#pragma unroll
    for (int i = 0; i < 8; ++i) s += gldP[t][i];
    gate[(size_t)bz * HWs + h * WW + w0 + t] = 1.f / (1.f + expf(-s));
  }
}

// ---- fused output v4: R12 structure, 512 threads (8 waves, 1 M-frag each).
// Same 64-px tile, same LDS (52.7 KB); staging = one (pixel,oct) per thread;
// accumulators halved -> occupancy up to 24 waves/CU.
__global__ __launch_bounds__(512) void fused_out_kernel(
    const ushort* __restrict__ xt, const float* __restrict__ offsp,
    const ushort* __restrict__ apk,
    const float* __restrict__ base_b, const float* __restrict__ def_b,
    const float* __restrict__ gate, float* __restrict__ out) {
  __shared__ ushort Win[4 * 68 * 64];   // 34,816 B  rows h-1..h+2, cols w0-2..w0+65
  __shared__ ushort Bt[2][64][64];      // 16,384 B  deform B tile (half channels)
  __shared__ float gvS[64];
  __shared__ float bbS[128], bdS[128];
  int t = threadIdx.x;
  int bid = blockIdx.x;
  int lin = (bid & 7) * 128 + (bid >> 3);
  int bz = lin >> 9;
  int rest = lin & 511;
  int h = rest >> 2, w0 = (rest & 3) << 6;
  int lane = t & 63, wid = t >> 6;      // wid = M-frag 0..7
  int l15 = lane & 15, lg = lane >> 4;
  int rq = lg << 2;
  const ushort* xtb = xt + (size_t)bz * 4194304;
  const bf16x8* APK = (const bf16x8*)apk;
  const u16x8 zv = (u16x8){0, 0, 0, 0, 0, 0, 0, 0};

  if (t < 64) gvS[t] = gate[(size_t)bz * HWs + h * WW + w0 + t];
  else if (t < 192) {
    int c = t - 64;
    bbS[c] = base_b[c];
    bdS[c] = def_b[c];
  }

  // per-thread pixel+oct (8 threads per pixel; one oct each)
  int p = t & 63, o = t >> 6;           // o in 0..7
  int mw = w0 + p;
  float oxr[9], oyr[9];
#pragma unroll
  for (int d = 0; d < 9; ++d) {
    oxr[d] = offsp[((size_t)bz * 18 + 2 * d) * HWs + h * WW + mw];
    oyr[d] = offsp[((size_t)bz * 18 + 2 * d + 1) * HWs + h * WW + mw];
  }

  f32x4 accB[4], accD[4];
#pragma unroll
  for (int nf = 0; nf < 4; ++nf) {
    accB[nf] = (f32x4){0.f, 0.f, 0.f, 0.f};
    accD[nf] = (f32x4){0.f, 0.f, 0.f, 0.f};
  }

  for (int half = 0; half < 2; ++half) {
    // ---- load window (coalesced, zero-fill OOB, slot-swizzled): 4x68 cells
    for (int it = 0; it < 5; ++it) {
      int u = it * 512 + t;
      if (u < 2176) {
        int s = u & 7;
        int c = (u >> 3) % 68;
        int r = u / 544;
        int gy = h - 1 + r, gx = w0 - 2 + c;
        u16x8 v = zv;
        if ((unsigned)gy < 128u && (unsigned)gx < 256u)
          v = *(const u16x8*)&xtb[((((size_t)gy << 8) + gx) << 7) + (half << 6) + (s << 3)];
        *(u16x8*)&Win[((r * 68 + c) << 6) + ((s ^ (c & 7)) << 3)] = v;
      }
    }
    __syncthreads();

    // ---- staging: deform tap d -> Bt[nb] (one oct per thread)
    auto stage = [&](int nb, int d) {
      float px = (float)mw + oxr[d], py = (float)h + oyr[d];
      float fx = floorf(px), fy = floorf(py);
      int x0 = (int)fx, y0 = (int)fy;
      float wx1 = px - fx, wy1 = py - fy;
      float wx0 = 1.f - wx1, wy0 = 1.f - wy1;
      int x1 = x0 + 1, y1 = y0 + 1;
      bool vx0 = (unsigned)x0 < 256u, vx1 = (unsigned)x1 < 256u;
      bool vy0 = (unsigned)y0 < 128u, vy1 = (unsigned)y1 < 128u;
      float g0 = (vx0 && vy0) ? wx0 * wy0 : 0.f;
      float g1 = (vx1 && vy0) ? wx1 * wy0 : 0.f;
      float g2 = (vx0 && vy1) ? wx0 * wy1 : 0.f;
      float g3 = (vx1 && vy1) ? wx1 * wy1 : 0.f;
      f32x2 G0 = (f32x2){g0, g0}, G1 = (f32x2){g1, g1};
      f32x2 G2 = (f32x2){g2, g2}, G3 = (f32x2){g3, g3};
      int cx0 = min(max(x0, 0), 255), cx1 = min(max(x1, 0), 255);
      int cy0 = min(max(y0, 0), 127), cy1 = min(max(y1, 0), 127);
      int rx0 = cx0 - w0 + 2, rx1 = cx1 - w0 + 2;
      int ry0 = cy0 - h + 1,  ry1 = cy1 - h + 1;
      bool i00 = ((unsigned)ry0 < 4u) && ((unsigned)rx0 < 68u);
      bool i01 = ((unsigned)ry0 < 4u) && ((unsigned)rx1 < 68u);
      bool i10 = ((unsigned)ry1 < 4u) && ((unsigned)rx0 < 68u);
      bool i11 = ((unsigned)ry1 < 4u) && ((unsigned)rx1 < 68u);
      int wb0 = ((ry0 * 68 + rx0) << 6) ^ ((rx0 & 7) << 3);
      int wb1 = ((ry0 * 68 + rx1) << 6) ^ ((rx1 & 7) << 3);
      int wb2 = ((ry1 * 68 + rx0) << 6) ^ ((rx0 & 7) << 3);
      int wb3 = ((ry1 * 68 + rx1) << 6) ^ ((rx1 & 7) << 3);
      int gb0 = (((cy0 << 8) + cx0) << 7) + (half << 6);
      int gb1 = (((cy0 << 8) + cx1) << 7) + (half << 6);
      int gb2 = (((cy1 << 8) + cx0) << 7) + (half << 6);
      int gb3 = (((cy1 << 8) + cx1) << 7) + (half << 6);
      int o8 = o << 3;
      uint4 c0, c1, c2, c3;
      if (i00) c0 = *(const uint4*)&Win[wb0 ^ o8];
      else     c0 = *(const uint4*)&xtb[gb0 + o8];
      if (i01) c1 = *(const uint4*)&Win[wb1 ^ o8];
      else     c1 = *(const uint4*)&xtb[gb1 + o8];
      if (i10) c2 = *(const uint4*)&Win[wb2 ^ o8];
      else     c2 = *(const uint4*)&xtb[gb2 + o8];
      if (i11) c3 = *(const uint4*)&Win[wb3 ^ o8];
      else     c3 = *(const uint4*)&xtb[gb3 + o8];
      uint4 r;
      r.x = comb4(c0.x, c1.x, c2.x, c3.x, G0, G1, G2, G3);
      r.y = comb4(c0.y, c1.y, c2.y, c3.y, G0, G1, G2, G3);
      r.z = comb4(c0.z, c1.z, c2.z, c3.z, G0, G1, G2, G3);
      r.w = comb4(c0.w, c1.w, c2.w, c3.w, G0, G1, G2, G3);
      *(uint4*)&Bt[nb][p][(o ^ (p & 7)) << 3] = r;
    };

    stage(0, 0);
    __syncthreads();

    int buf = 0;
    for (int d = 0; d < 9; ++d) {
      // ---- MFMA: base tap d (from Win) + deform tap d (from Bt[buf])
      int ky = d / 3 - 1, kx = d % 3 - 1;
      int ryB = ky + 1;
#pragma unroll
      for (int kfi = 0; kfi < 2; ++kfi) {
        int kff = half * 2 + kfi;
        int segk = kfi * 4 + lg;
        bf16x8 aB = APK[(size_t)((d * 8 + wid) * 4 + kff) * 64 + lane];
        bf16x8 aD = APK[(size_t)(((9 + d) * 8 + wid) * 4 + kff) * 64 + lane];
#pragma unroll
        for (int nf = 0; nf < 4; ++nf) {
          int pix = nf * 16 + l15;
          int cxr = pix + kx + 2;
          bf16x8 bB = *(const bf16x8*)&Win[((ryB * 68 + cxr) << 6) + ((segk ^ (cxr & 7)) << 3)];
          bf16x8 bD = *(const bf16x8*)&Bt[buf][pix][(segk ^ (pix & 7)) << 3];
          accB[nf] = __builtin_amdgcn_mfma_f32_16x16x32_bf16(aB, bB, accB[nf], 0, 0, 0);
          accD[nf] = __builtin_amdgcn_mfma_f32_16x16x32_bf16(aD, bD, accD[nf], 0, 0, 0);
        }
      }
      if (d < 8) stage(buf ^ 1, d + 1);
      __syncthreads();
      buf ^= 1;
    }
    if (half == 0) __syncthreads();   // window overwrite safety for next half
  }

  // ---- epilogue: gated blend
#pragma unroll
  for (int nf = 0; nf < 4; ++nf) {
    int pix = nf * 16 + l15;
    float gv = gvS[pix], go = 1.f - gv;
    int w = w0 + pix;
#pragma unroll
    for (int r = 0; r < 4; ++r) {
      int oc = wid * 16 + rq + r;
      out[(((size_t)bz * CC + oc) << 15) + h * WW + w] =
          go * (accB[nf][r] + bbS[oc]) + gv * (accD[nf][r] + bdS[oc]);
    }
  }
}

extern "C" void kernel_launch(void* const* d_in, const int* in_sizes, int n_in,
                              void* d_out, int out_size, void* d_ws, size_t ws_size,
                              hipStream_t stream) {
  const float* x        = (const float*)d_in[0];
  const float* offset_w = (const float*)d_in[1];
  const float* offset_b = (const float*)d_in[2];
  const float* gate_w1  = (const float*)d_in[3];
  const float* gate_b1  = (const float*)d_in[4];
  const float* gate_w2  = (const float*)d_in[5];
  const float* gate_b2  = (const float*)d_in[6];
  const float* base_w   = (const float*)d_in[7];
  const float* base_b   = (const float*)d_in[8];
  const float* def_w    = (const float*)d_in[9];
  const float* def_b    = (const float*)d_in[10];
  float* out = (float*)d_out;
  float* ws  = (float*)d_ws;

  float* offsb   = ws;                          // 1,179,648 f
  float* gatebuf = offsb + 1179648;             //    65,536 f
  float* fe      = gatebuf + 65536;             //    33,024 f
  float* magbuf  = fe + 33024;                  // 4,718,592 f
  ushort* xt     = (ushort*)(magbuf + 4718592); // 16,777,216 ush
  ushort* F1     = xt + 16777216;               //  9,437,184 ush
  ushort* a1pk   = F1 + 9437184;                //     81,920 ush
  ushort* a2pk   = a1pk + 81920;                //     65,536 ush
  ushort* apkF   = a2pk + 65536;                //    294,912 ush
  ushort* apkA   = apkF + 294912;               //    138,240 ush
  // total ~77.6 MB

  hipMemsetAsync(fe, 0, 33024 * sizeof(float), stream);
  prep_kernel<<<1308, 256, 0, stream>>>(base_w, def_w, offset_w, gate_w1, x,
                                        apkF, apkA, a1pk, a2pk, xt);

  dft1_kernel<<<512, 256, 0, stream>>>(x, a1pk, F1);
  dft2_kernel<<<768, 256, 0, stream>>>(F1, a2pk, magbuf);
  fe_reduce_kernel<<<1152, 256, 0, stream>>>(magbuf, fe);

  aux_conv_kernel<<<1024, 256, 0, stream>>>(xt, fe, apkA, offset_b, gate_b1,
                                            gate_w2, gate_b2, offsb, gatebuf);

  fused_out_kernel<<<1024, 512, 0, stream>>>(xt, offsb, apkF, base_b, def_b,
                                             gatebuf, out);
}

// Round 16
// 195.409 us; speedup vs baseline: 1.6111x; 1.6111x over previous
//
#include <hip/hip_runtime.h>
#include <hip/hip_bf16.h>

#define BB 2
#define CC 128
#define HH 128
#define WW 256
#define HWs (HH*WW)          // 32768
#define PI_F 3.14159265358979323846f

typedef __attribute__((ext_vector_type(8))) short bf16x8;
typedef __attribute__((ext_vector_type(8))) unsigned short u16x8;
typedef __attribute__((ext_vector_type(4))) float f32x4;
typedef __attribute__((ext_vector_type(2))) float f32x2;

__device__ __forceinline__ ushort f2bf(float f) {   // RNE
  uint u = __float_as_uint(f);
  u = (u + 0x7fffu + ((u >> 16) & 1u)) >> 16;
  return (ushort)u;
}
__device__ __forceinline__ float bf2f(ushort u) {
  return __uint_as_float(((uint)u) << 16);
}
// combine 4 bf16-pairs (uint each) with weights -> packed bf16 pair (pk-fma)
__device__ __forceinline__ uint comb4(uint u0, uint u1, uint u2, uint u3,
                                      f32x2 g0, f32x2 g1, f32x2 g2, f32x2 g3) {
  f32x2 a0 = (f32x2){__uint_as_float(u0 << 16), __uint_as_float(u0 & 0xffff0000u)};
  f32x2 a1 = (f32x2){__uint_as_float(u1 << 16), __uint_as_float(u1 & 0xffff0000u)};
  f32x2 a2 = (f32x2){__uint_as_float(u2 << 16), __uint_as_float(u2 & 0xffff0000u)};
  f32x2 a3 = (f32x2){__uint_as_float(u3 << 16), __uint_as_float(u3 & 0xffff0000u)};
  f32x2 s = a0 * g0 + a1 * g1 + a2 * g2 + a3 * g3;   // v_pk_fma_f32
  uint ua = __float_as_uint(s.x) + 0x8000u;
  uint ub = __float_as_uint(s.y) + 0x8000u;
  return (ua >> 16) | (ub & 0xffff0000u);
}

// ---- fused: weight/twiddle packing (blocks 0..283) + x->xt NHWC transpose
__global__ __launch_bounds__(256) void prep_kernel(
    const float* __restrict__ bw, const float* __restrict__ dw,
    const float* __restrict__ ow, const float* __restrict__ gw,
    const float* __restrict__ x,
    ushort* __restrict__ apkF, ushort* __restrict__ apkA,
    ushort* __restrict__ a1, ushort* __restrict__ a2,
    ushort* __restrict__ xt) {
  __shared__ ushort sT[64][128];
  int bid = blockIdx.x;
  int tid = threadIdx.x;
  if (bid >= 284) {
    int blk = bid - 284;              // 1024 = 2b * 128h * 4wt
    int wt = blk & 3, h = (blk >> 2) & 127, b = blk >> 9;
    int t = tid;
    const float* xb = x + ((size_t)b * CC * HH + h) * WW;
    ushort* ob = xt + (((size_t)b * HH + h) * WW) * 128;
    {
      int w = t & 63;
      int sw = (w & 7) << 3;
#pragma unroll
      for (int it = 0; it < 4; ++it) {
        int oct = (t >> 6) + it * 4;
        u16x8 v;
#pragma unroll
        for (int j = 0; j < 8; ++j)
          v[j] = f2bf(xb[(size_t)(oct * 8 + j) * HWs + wt * 64 + w]);
        *(u16x8*)&sT[w][(oct << 3) ^ sw] = v;
      }
    }
    __syncthreads();
#pragma unroll
    for (int it = 0; it < 4; ++it) {
      int u = t + it * 256;
      int w = u >> 4, oct = u & 15;
      u16x8 v = *(const u16x8*)&sT[w][(oct << 3) ^ ((w & 7) << 3)];
      *(u16x8*)&ob[(size_t)(wt * 64 + w) * 128 + oct * 8] = v;
    }
    return;
  }
  if (bid < 144) {
    int gid = bid * 256 + tid;
    int lane = gid & 63;
    int kf = (gid >> 6) & 3;
    int mf = (gid >> 8) & 7;
    int chunk = gid >> 11;
    int part = chunk >= 9;
    int tap = part ? chunk - 9 : chunk;
    int m = mf * 16 + (lane & 15);
    int cb = kf * 32 + ((lane >> 4) << 3);
    const float* src = part ? dw : bw;
    ushort* dst = apkF + (size_t)gid * 8;
#pragma unroll
    for (int j = 0; j < 8; ++j)
      dst[j] = f2bf(src[(size_t)m * 1152 + (size_t)(cb + j) * 9 + tap]);
  } else if (bid < 212) {
    int gid = (bid - 144) * 256 + tid;
    if (gid >= 17280) return;
    int lane = gid & 63;
    int kf = (gid >> 6) % 5;
    int mf = (gid / 320) % 6;
    int tap = gid / 1920;
    int m = mf * 16 + (lane & 15);
    int cb = kf * 32 + ((lane >> 4) << 3);
#pragma unroll
    for (int j = 0; j < 8; ++j) {
      int c = cb + j;
      float v = 0.f;
      if (c < 133) {
        if (m < 18) v = ow[(size_t)m * 1197 + c * 9 + tap];
        else if (m < 84) v = gw[(size_t)(m - 18) * 1197 + c * 9 + tap];
      }
      apkA[(size_t)gid * 8 + j] = f2bf(v);
    }
  } else {
    int gid = (bid - 212) * 256 + tid;
    if (gid < 10240) {
      int lane = gid & 63, kf = (gid >> 6) & 7, mf = gid >> 9;
      int m = mf * 16 + (lane & 15);
      int kk0 = kf * 32 + ((lane >> 4) << 3);
#pragma unroll
      for (int j = 0; j < 8; ++j) {
        int kk = kk0 + j;
        float v = 0.f;
        if (m < 129)      { int tt = (m * kk) & 255;         v =  cosf(tt * (PI_F / 128.f)); }
        else if (m < 258) { int tt = ((m - 129) * kk) & 255; v = -sinf(tt * (PI_F / 128.f)); }
        a1[(size_t)gid * 8 + j] = f2bf(v);
      }
    } else if (gid < 18432) {
      int q = gid - 10240;
      int lane = q & 63, kf = (q >> 6) & 7, mf = q >> 9;
      int m = mf * 16 + (lane & 15);
      int g = m & 127;
      int kk0 = kf * 32 + ((lane >> 4) << 3);
#pragma unroll
      for (int j = 0; j < 8; ++j) {
        int kk = kk0 + j;
        int h2 = kk & 127;
        int tt = (g * h2) & 127;
        float ang = tt * (PI_F / 64.f);
        float v = (m < 128) ? ((kk < 128) ? cosf(ang) : sinf(ang))
                            : ((kk < 128) ? -sinf(ang) : cosf(ang));
        a2[(size_t)q * 8 + j] = f2bf(v);
      }
    }
  }
}

// ---- DFT stage 1 (along W), MFMA. Grid 512: (bc, nh) split.
__global__ __launch_bounds__(256) void dft1_kernel(const float* __restrict__ x,
    const ushort* __restrict__ a1pk, ushort* __restrict__ F1) {
  int bid = blockIdx.x;
  int bc = bid >> 1, nh = bid & 1;
  int t = threadIdx.x, lane = t & 63, wv = t >> 6;
  int q8 = (lane >> 4) << 3, rq = (lane >> 4) << 2;
  const bf16x8* APK = (const bf16x8*)a1pk;
  ushort* f1b = F1 + (size_t)bc * 36864;
  f32x4 acc[5][4];
#pragma unroll
  for (int i = 0; i < 5; ++i)
#pragma unroll
    for (int n = 0; n < 4; ++n) acc[i][n] = (f32x4){0.f, 0.f, 0.f, 0.f};
  for (int kf = 0; kf < 8; ++kf) {
    bf16x8 av[5];
#pragma unroll
    for (int i = 0; i < 5; ++i)
      av[i] = APK[(size_t)((wv * 5 + i) * 8 + kf) * 64 + lane];
#pragma unroll
    for (int n2 = 0; n2 < 4; ++n2) {
      int nf = nh * 4 + n2;
      int hh = nf * 16 + (lane & 15);
      const float* xp = x + (((size_t)bc * HH + hh) << 8) + kf * 32 + q8;
      float4 xa = *(const float4*)xp;
      float4 xb4 = *(const float4*)(xp + 4);
      bf16x8 bv;
      bv[0] = (short)f2bf(xa.x); bv[1] = (short)f2bf(xa.y);
      bv[2] = (short)f2bf(xa.z); bv[3] = (short)f2bf(xa.w);
      bv[4] = (short)f2bf(xb4.x); bv[5] = (short)f2bf(xb4.y);
      bv[6] = (short)f2bf(xb4.z); bv[7] = (short)f2bf(xb4.w);
#pragma unroll
      for (int i = 0; i < 5; ++i)
        acc[i][n2] = __builtin_amdgcn_mfma_f32_16x16x32_bf16(av[i], bv, acc[i][n2], 0, 0, 0);
    }
  }
#pragma unroll
  for (int n2 = 0; n2 < 4; ++n2) {
    int hh = (nh * 4 + n2) * 16 + (lane & 15);
#pragma unroll
    for (int i = 0; i < 5; ++i) {
#pragma unroll
      for (int r = 0; r < 4; ++r) {
        int m = (wv * 5 + i) * 16 + rq + r;
        if (m < 258) {
          int sel = m >= 129;
          int k = sel ? m - 129 : m;
          f1b[(size_t)k * 256 + sel * 128 + hh] = f2bf(acc[i][n2][r]);
        }
      }
    }
  }
}

// ---- DFT stage 2 (along H) + magnitude. Grid 768: (bc, ng) split.
__global__ __launch_bounds__(256) void dft2_kernel(const ushort* __restrict__ F1,
    const ushort* __restrict__ a2pk, float* __restrict__ magbuf) {
  int bid = blockIdx.x;
  int bc = bid / 3, ng = bid % 3;
  int t = threadIdx.x, lane = t & 63, wv = t >> 6;
  int q8 = (lane >> 4) << 3, rq = (lane >> 4) << 2;
  const bf16x8* APK = (const bf16x8*)a2pk;
  const ushort* f1b = F1 + (size_t)bc * 36864;
  float* mb = magbuf + (size_t)bc * 18432;
  f32x4 acc[4][3];
#pragma unroll
  for (int i = 0; i < 4; ++i)
#pragma unroll
    for (int n = 0; n < 3; ++n) acc[i][n] = (f32x4){0.f, 0.f, 0.f, 0.f};
  for (int kf = 0; kf < 8; ++kf) {
    bf16x8 av[4];
#pragma unroll
    for (int i = 0; i < 4; ++i) {
      int mf = (i < 2) ? (2 * wv + i) : (2 * wv + (i - 2) + 8);
      av[i] = APK[(size_t)(mf * 8 + kf) * 64 + lane];
    }
#pragma unroll
    for (int n2 = 0; n2 < 3; ++n2) {
      int nf = ng * 3 + n2;
      int krow = nf * 16 + (lane & 15);
      bf16x8 bv = *(const bf16x8*)&f1b[(size_t)krow * 256 + kf * 32 + q8];
#pragma unroll
      for (int i = 0; i < 4; ++i)
        acc[i][n2] = __builtin_amdgcn_mfma_f32_16x16x32_bf16(av[i], bv, acc[i][n2], 0, 0, 0);
    }
  }
#pragma unroll
  for (int n2 = 0; n2 < 3; ++n2) {
    int k = (ng * 3 + n2) * 16 + (lane & 15);
    if (k < 129) {
#pragma unroll
      for (int pr = 0; pr < 2; ++pr) {
#pragma unroll
        for (int r = 0; r < 4; ++r) {
          int g = (2 * wv + pr) * 16 + rq + r;
          float vr = acc[pr][n2][r], vi = acc[pr + 2][n2][r];
          mb[(size_t)g * 144 + k] = sqrtf(vr * vr + vi * vi);
        }
      }
    }
  }
}

// ---- reduce magnitude over channels -> fe[b][g][129].
__global__ __launch_bounds__(256) void fe_reduce_kernel(const float* __restrict__ magbuf,
    float* __restrict__ fe) {
  int bid = blockIdx.x;
  int i = (bid >> 3) * 256 + threadIdx.x;   // 36864
  int cq = bid & 7;
  if (i >= 36864) return;
  int k = i % 144;
  int gb = i / 144;
  int g = gb & 127, b = gb >> 7;
  if (k >= 129) return;
  const float* mp = magbuf + (size_t)b * 128 * 18432 + (size_t)g * 144 + k
                  + (size_t)cq * 16 * 18432;
  float s = 0.f;
#pragma unroll
  for (int c = 0; c < 16; ++c) s += mp[(size_t)c * 18432];
  atomicAdd(&fe[((size_t)b * 128 + g) * 129 + k],
            s * (1.0f / (181.01933598375618f * 128.0f)));
}

// ---- aux conv v2: 3-row LDS window per channel-half, B-fragments read
// directly from window (no per-tap staging/barriers). coord/fe channels in
// a small tile consumed by kf=4 (half 1 only). Gate 1x1 reduced via gldP.
__global__ __launch_bounds__(256) void aux_conv_kernel(
    const ushort* __restrict__ xt, const float* __restrict__ fe,
    const ushort* __restrict__ apk,
    const float* __restrict__ offset_b, const float* __restrict__ gate_b1,
    const float* __restrict__ w2, const float* __restrict__ b2,
    float* __restrict__ offs, float* __restrict__ gate) {
  __shared__ ushort Win3[3 * 68 * 64];   // 26,112 B
  __shared__ ushort coordS[204 * 8];     // 3,264 B
  __shared__ float gldP[64][8];          // 2,048 B
  int t = threadIdx.x;
  int bid = blockIdx.x;
  int lin = (bid & 7) * 128 + (bid >> 3);
  int bz = lin >> 9;
  int rest = lin & 511;
  int h = rest >> 2, w0 = (rest & 3) << 6;
  int lane = t & 63, wid = t >> 6;
  int wm = wid >> 1, wn = wid & 1;
  int l15 = lane & 15, lg = lane >> 4;
  int rq = lg << 2;
  const bf16x8* APK = (const bf16x8*)apk;
  const ushort* xtb = xt + (size_t)bz * 4194304;
  const bf16x8 zvb = (bf16x8){0, 0, 0, 0, 0, 0, 0, 0};

  if (t < 204) {
    int r = t / 68, c = t - r * 68;
    int gy = h - 1 + r, gx = w0 - 2 + c;
    u16x8 v = (u16x8){0, 0, 0, 0, 0, 0, 0, 0};
    if ((unsigned)gy < 128u && (unsigned)gx < 256u) {
      float th = -PI_F + (float)gx * (2.0f * PI_F / 255.0f);
      float ph = -0.5f * PI_F + (float)gy * (PI_F / 127.0f);
      float sxc = ((float)gx + 0.5f) * (129.0f / 256.0f) - 0.5f;
      float fx = floorf(sxc);
      int x0 = (int)fx;
      float fr = sxc - fx;
      int x1 = min(x0 + 1, 128);
      x0 = max(x0, 0);
      const float* fb = fe + ((size_t)bz * 128 + gy) * 129;
      float fv = fb[x0] * (1.f - fr) + fb[x1] * fr;
      v[0] = f2bf(sinf(th)); v[1] = f2bf(cosf(th));
      v[2] = f2bf(sinf(ph)); v[3] = f2bf(cosf(ph));
      v[4] = f2bf(fv);
    }
    *(u16x8*)&coordS[t * 8] = v;
  }

  f32x4 acc[3][2];
#pragma unroll
  for (int i = 0; i < 3; ++i) {
    acc[i][0] = (f32x4){0.f, 0.f, 0.f, 0.f};
    acc[i][1] = (f32x4){0.f, 0.f, 0.f, 0.f};
  }
  int p0 = wn * 32 + l15, p1 = p0 + 16;

  for (int half = 0; half < 2; ++half) {
    if (half) __syncthreads();
    for (int it = 0; it < 7; ++it) {
      int u = it * 256 + t;
      if (u < 1632) {
        int s = u & 7;
        int c = (u >> 3) % 68;
        int r = u / 544;
        int gy = h - 1 + r, gx = w0 - 2 + c;
        u16x8 v = (u16x8){0, 0, 0, 0, 0, 0, 0, 0};
        if ((unsigned)gy < 128u && (unsigned)gx < 256u)
          v = *(const u16x8*)&xtb[((((size_t)gy << 8) + gx) << 7) + (half << 6) + (s << 3)];
        *(u16x8*)&Win3[((r * 68 + c) << 6) + ((s ^ (c & 7)) << 3)] = v;
      }
    }
    __syncthreads();

    for (int tap = 0; tap < 9; ++tap) {
      int ky = tap / 3 - 1, kx = tap % 3 - 1;
      int rr = ky + 1;
      int c0 = p0 + kx + 2, c1 = p1 + kx + 2;
      int nkf = half ? 3 : 2;
      for (int kfi = 0; kfi < nkf; ++kfi) {
        bf16x8 b0, b1;
        int kf;
        if (kfi < 2) {
          kf = half * 2 + kfi;
          int s = kfi * 4 + lg;
          b0 = *(const bf16x8*)&Win3[((rr * 68 + c0) << 6) + ((s ^ (c0 & 7)) << 3)];
          b1 = *(const bf16x8*)&Win3[((rr * 68 + c1) << 6) + ((s ^ (c1 & 7)) << 3)];
        } else {
          kf = 4;
          b0 = (lg == 0) ? *(const bf16x8*)&coordS[(rr * 68 + c0) * 8] : zvb;
          b1 = (lg == 0) ? *(const bf16x8*)&coordS[(rr * 68 + c1) * 8] : zvb;
        }
        int fb = (tap * 6 + wm * 3) * 5 + kf;
#pragma unroll
        for (int mfi = 0; mfi < 3; ++mfi) {
          bf16x8 av = APK[(size_t)(fb + mfi * 5) * 64 + lane];
          acc[mfi][0] = __builtin_amdgcn_mfma_f32_16x16x32_bf16(av, b0, acc[mfi][0], 0, 0, 0);
          acc[mfi][1] = __builtin_amdgcn_mfma_f32_16x16x32_bf16(av, b1, acc[mfi][1], 0, 0, 0);
        }
      }
    }
  }

  float gp[2] = {0.f, 0.f};
#pragma unroll
  for (int nf = 0; nf < 2; ++nf) {
    int p = wn * 32 + nf * 16 + l15;
    int w = w0 + p;
#pragma unroll
    for (int mfi = 0; mfi < 3; ++mfi) {
#pragma unroll
      for (int r = 0; r < 4; ++r) {
        int oc = wm * 48 + mfi * 16 + rq + r;
        float v = acc[mfi][nf][r];
        if (oc < 18) {
          offs[((size_t)bz * 18 + oc) * HWs + h * WW + w] = v + offset_b[oc];
        } else if (oc < 84) {
          gp[nf] += w2[oc - 18] * fmaxf(v + gate_b1[oc - 18], 0.f);
        }
      }
    }
  }
  gldP[p0][wm * 4 + lg] = gp[0];
  gldP[p1][wm * 4 + lg] = gp[1];
  __syncthreads();
  if (t < 64) {
    float s = b2[0];
#pragma unroll
    for (int i = 0; i < 8; ++i) s += gldP[t][i];
    gate[(size_t)bz * HWs + h * WW + w0 + t] = 1.f / (1.f + expf(-s));
  }
}

// ---- fused output: R6/R10 structure (113 us stable), pk-fma combine.
__global__ __launch_bounds__(256) void fused_out_kernel(
    const ushort* __restrict__ xt, const float* __restrict__ offsp,
    const ushort* __restrict__ apk,
    const float* __restrict__ base_b, const float* __restrict__ def_b,
    const float* __restrict__ gate, float* __restrict__ out) {
  __shared__ ushort Win[4 * 68 * 64];   // 34,816 B  rows h-1..h+2, cols w0-2..w0+65
  __shared__ ushort Bt[2][64][64];      // 16,384 B  deform B tile (half channels)
  __shared__ float gvS[64];
  __shared__ float bbS[128], bdS[128];
  int t = threadIdx.x;
  int bid = blockIdx.x;
  int lin = (bid & 7) * 128 + (bid >> 3);
  int bz = lin >> 9;
  int rest = lin & 511;
  int h = rest >> 2, w0 = (rest & 3) << 6;
  int lane = t & 63, wv = t >> 6;
  int l15 = lane & 15, lg = lane >> 4;
  int rq = lg << 2;
  const ushort* xtb = xt + (size_t)bz * 4194304;
  const bf16x8* APK = (const bf16x8*)apk;
  const u16x8 zv = (u16x8){0, 0, 0, 0, 0, 0, 0, 0};

  if (t < 64) gvS[t] = gate[(size_t)bz * HWs + h * WW + w0 + t];
  else if (t < 192) {
    int c = t - 64;
    bbS[c] = base_b[c];
    bdS[c] = def_b[c];
  }

  // per-thread pixel (4 threads per pixel; octs o4, o4+4)
  int p = t & 63, o4 = t >> 6;
  int mw = w0 + p;
  float oxr[9], oyr[9];
#pragma unroll
  for (int d = 0; d < 9; ++d) {
    oxr[d] = offsp[((size_t)bz * 18 + 2 * d) * HWs + h * WW + mw];
    oyr[d] = offsp[((size_t)bz * 18 + 2 * d + 1) * HWs + h * WW + mw];
  }

  f32x4 accB[2][4], accD[2][4];
#pragma unroll
  for (int mi = 0; mi < 2; ++mi)
#pragma unroll
    for (int nf = 0; nf < 4; ++nf) {
      accB[mi][nf] = (f32x4){0.f, 0.f, 0.f, 0.f};
      accD[mi][nf] = (f32x4){0.f, 0.f, 0.f, 0.f};
    }

  for (int half = 0; half < 2; ++half) {
    // ---- load window (coalesced, zero-fill OOB, slot-swizzled): 4x68 cells
#pragma unroll
    for (int it = 0; it < 9; ++it) {
      int u = it * 256 + t;
      if (u < 2176) {
        int s = u & 7;
        int c = (u >> 3) % 68;
        int r = u / 544;
        int gy = h - 1 + r, gx = w0 - 2 + c;
        u16x8 v = zv;
        if ((unsigned)gy < 128u && (unsigned)gx < 256u)
          v = *(const u16x8*)&xtb[((((size_t)gy << 8) + gx) << 7) + (half << 6) + (s << 3)];
        *(u16x8*)&Win[((r * 68 + c) << 6) + ((s ^ (c & 7)) << 3)] = v;
      }
    }
    __syncthreads();

    // ---- staging helper: deform tap d -> Bt[nb]
    auto stage = [&](int nb, int d) {
      float px = (float)mw + oxr[d], py = (float)h + oyr[d];
      float fx = floorf(px), fy = floorf(py);
      int x0 = (int)fx, y0 = (int)fy;
      float wx1 = px - fx, wy1 = py - fy;
      float wx0 = 1.f - wx1, wy0 = 1.f - wy1;
      int x1 = x0 + 1, y1 = y0 + 1;
      bool vx0 = (unsigned)x0 < 256u, vx1 = (unsigned)x1 < 256u;
      bool vy0 = (unsigned)y0 < 128u, vy1 = (unsigned)y1 < 128u;
      float g0 = (vx0 && vy0) ? wx0 * wy0 : 0.f;
      float g1 = (vx1 && vy0) ? wx1 * wy0 : 0.f;
      float g2 = (vx0 && vy1) ? wx0 * wy1 : 0.f;
      float g3 = (vx1 && vy1) ? wx1 * wy1 : 0.f;
      f32x2 G0 = (f32x2){g0, g0}, G1 = (f32x2){g1, g1};
      f32x2 G2 = (f32x2){g2, g2}, G3 = (f32x2){g3, g3};
      int cx0 = min(max(x0, 0), 255), cx1 = min(max(x1, 0), 255);
      int cy0 = min(max(y0, 0), 127), cy1 = min(max(y1, 0), 127);
      int rx0 = cx0 - w0 + 2, rx1 = cx1 - w0 + 2;
      int ry0 = cy0 - h + 1,  ry1 = cy1 - h + 1;
      bool i00 = ((unsigned)ry0 < 4u) && ((unsigned)rx0 < 68u);
      bool i01 = ((unsigned)ry0 < 4u) && ((unsigned)rx1 < 68u);
      bool i10 = ((unsigned)ry1 < 4u) && ((unsigned)rx0 < 68u);
      bool i11 = ((unsigned)ry1 < 4u) && ((unsigned)rx1 < 68u);
      int wb0 = ((ry0 * 68 + rx0) << 6) ^ ((rx0 & 7) << 3);
      int wb1 = ((ry0 * 68 + rx1) << 6) ^ ((rx1 & 7) << 3);
      int wb2 = ((ry1 * 68 + rx0) << 6) ^ ((rx0 & 7) << 3);
      int wb3 = ((ry1 * 68 + rx1) << 6) ^ ((rx1 & 7) << 3);
      int gb0 = (((cy0 << 8) + cx0) << 7) + (half << 6);
      int gb1 = (((cy0 << 8) + cx1) << 7) + (half << 6);
      int gb2 = (((cy1 << 8) + cx0) << 7) + (half << 6);
      int gb3 = (((cy1 << 8) + cx1) << 7) + (half << 6);
#pragma unroll
      for (int oo = 0; oo < 2; ++oo) {
        int o = o4 + oo * 4;
        int o8 = o << 3;
        uint4 c0, c1, c2, c3;
        if (i00) c0 = *(const uint4*)&Win[wb0 ^ o8];
        else     c0 = *(const uint4*)&xtb[gb0 + o8];
        if (i01) c1 = *(const uint4*)&Win[wb1 ^ o8];
        else     c1 = *(const uint4*)&xtb[gb1 + o8];
        if (i10) c2 = *(const uint4*)&Win[wb2 ^ o8];
        else     c2 = *(const uint4*)&xtb[gb2 + o8];
        if (i11) c3 = *(const uint4*)&Win[wb3 ^ o8];
        else     c3 = *(const uint4*)&xtb[gb3 + o8];
        uint4 r;
        r.x = comb4(c0.x, c1.x, c2.x, c3.x, G0, G1, G2, G3);
        r.y = comb4(c0.y, c1.y, c2.y, c3.y, G0, G1, G2, G3);
        r.z = comb4(c0.z, c1.z, c2.z, c3.z, G0, G1, G2, G3);
        r.w = comb4(c0.w, c1.w, c2.w, c3.w, G0, G1, G2, G3);
        *(uint4*)&Bt[nb][p][(o ^ (p & 7)) << 3] = r;
      }
    };

    stage(0, 0);
    __syncthreads();

    int buf = 0;
    for (int d = 0; d < 9; ++d) {
      // ---- MFMA: base tap d (from Win) + deform tap d (from Bt[buf])
      int ky = d / 3 - 1, kx = d % 3 - 1;
      int ryB = ky + 1;
#pragma unroll
      for (int kfi = 0; kfi < 2; ++kfi) {
        int kff = half * 2 + kfi;
        int segk = kfi * 4 + lg;
        bf16x8 aB0 = APK[(size_t)((d * 8 + wv) * 4 + kff) * 64 + lane];
        bf16x8 aB1 = APK[(size_t)((d * 8 + wv + 4) * 4 + kff) * 64 + lane];
        bf16x8 aD0 = APK[(size_t)(((9 + d) * 8 + wv) * 4 + kff) * 64 + lane];
        bf16x8 aD1 = APK[(size_t)(((9 + d) * 8 + wv + 4) * 4 + kff) * 64 + lane];
#pragma unroll
        for (int nf = 0; nf < 4; ++nf) {
          int pix = nf * 16 + l15;
          int cxr = pix + kx + 2;
          bf16x8 bB = *(const bf16x8*)&Win[((ryB * 68 + cxr) << 6) + ((segk ^ (cxr & 7)) << 3)];
          bf16x8 bD = *(const bf16x8*)&Bt[buf][pix][(segk ^ (pix & 7)) << 3];
          accB[0][nf] = __builtin_amdgcn_mfma_f32_16x16x32_bf16(aB0, bB, accB[0][nf], 0, 0, 0);
          accB[1][nf] = __builtin_amdgcn_mfma_f32_16x16x32_bf16(aB1, bB, accB[1][nf], 0, 0, 0);
          accD[0][nf] = __builtin_amdgcn_mfma_f32_16x16x32_bf16(aD0, bD, accD[0][nf], 0, 0, 0);
          accD[1][nf] = __builtin_amdgcn_mfma_f32_16x16x32_bf16(aD1, bD, accD[1][nf], 0, 0, 0);
        }
      }
      if (d < 8) stage(buf ^ 1, d + 1);
      __syncthreads();
      buf ^= 1;
    }
    if (half == 0) __syncthreads();   // window overwrite safety for next half
  }

  // ---- epilogue: gated blend
#pragma unroll
  for (int nf = 0; nf < 4; ++nf) {
    int pix = nf * 16 + l15;
    float gv = gvS[pix], go = 1.f - gv;
    int w = w0 + pix;
#pragma unroll
    for (int mi = 0; mi < 2; ++mi) {
      int mf = wv + mi * 4;
#pragma unroll
      for (int r = 0; r < 4; ++r) {
        int oc = mf * 16 + rq + r;
        out[(((size_t)bz * CC + oc) << 15) + h * WW + w] =
            go * (accB[mi][nf][r] + bbS[oc]) + gv * (accD[mi][nf][r] + bdS[oc]);
      }
    }
  }
}

extern "C" void kernel_launch(void* const* d_in, const int* in_sizes, int n_in,
                              void* d_out, int out_size, void* d_ws, size_t ws_size,
                              hipStream_t stream) {
  const float* x        = (const float*)d_in[0];
  const float* offset_w = (const float*)d_in[1];
  const float* offset_b = (const float*)d_in[2];
  const float* gate_w1  = (const float*)d_in[3];
  const float* gate_b1  = (const float*)d_in[4];
  const float* gate_w2  = (const float*)d_in[5];
  const float* gate_b2  = (const float*)d_in[6];
  const float* base_w   = (const float*)d_in[7];
  const float* base_b   = (const float*)d_in[8];
  const float* def_w    = (const float*)d_in[9];
  const float* def_b    = (const float*)d_in[10];
  float* out = (float*)d_out;
  float* ws  = (float*)d_ws;

  float* offsb   = ws;                          // 1,179,648 f
  float* gatebuf = offsb + 1179648;             //    65,536 f
  float* fe      = gatebuf + 65536;             //    33,024 f
  float* magbuf  = fe + 33024;                  // 4,718,592 f
  ushort* xt     = (ushort*)(magbuf + 4718592); // 16,777,216 ush
  ushort* F1     = xt + 16777216;               //  9,437,184 ush
  ushort* a1pk   = F1 + 9437184;                //     81,920 ush
  ushort* a2pk   = a1pk + 81920;                //     65,536 ush
  ushort* apkF   = a2pk + 65536;                //    294,912 ush
  ushort* apkA   = apkF + 294912;               //    138,240 ush
  // total ~77.6 MB

  hipMemsetAsync(fe, 0, 33024 * sizeof(float), stream);
  prep_kernel<<<1308, 256, 0, stream>>>(base_w, def_w, offset_w, gate_w1, x,
                                        apkF, apkA, a1pk, a2pk, xt);

  dft1_kernel<<<512, 256, 0, stream>>>(x, a1pk, F1);
  dft2_kernel<<<768, 256, 0, stream>>>(F1, a2pk, magbuf);
  fe_reduce_kernel<<<1152, 256, 0, stream>>>(magbuf, fe);

  aux_conv_kernel<<<1024, 256, 0, stream>>>(xt, fe, apkA, offset_b, gate_b1,
                                            gate_w2, gate_b2, offsb, gatebuf);

  fused_out_kernel<<<1024, 256, 0, stream>>>(xt, offsb, apkF, base_b, def_b,
                                             gatebuf, out);
}